// Round 10
// baseline (59.393 us; speedup 1.0000x reference)
//
#include <hip/hip_runtime.h>

typedef _Float16 f16;
typedef __attribute__((ext_vector_type(8))) _Float16 f16x8;
typedef __attribute__((ext_vector_type(4))) _Float16 f16x4;
typedef __attribute__((ext_vector_type(4))) float f32x4;

#define HWB 16384

// K layout (both GEMMs): k = kk*64 + c, 18 k-steps of 32 (ch-half in {0,1}).
// A-frag packs: lane l of k-step t, M-tile m holds W[o = m*16 + (l&15)]
//               [c = (t&1)*32 + (l>>4)*8 + j], kk = t>>1.
// wdef_ap: [t(18)][m(4)][lane(64)][j(8)] f16 = 73728 B
// woff_ap: [t(18)][m(2)][lane(64)][j(8)] f16 = 36864 B (o>=18 zero)

__device__ __forceinline__ void prep_elem(int i,
                                          const float* __restrict__ w_off,
                                          const float* __restrict__ w_def,
                                          f16* __restrict__ wdef_ap,
                                          f16* __restrict__ woff_ap) {
    if (i < 36864) {
        int j = i & 7, l = (i >> 3) & 63, m = (i >> 9) & 3, t = i >> 11;
        int kk = t >> 1, ch = t & 1;
        int o = m * 16 + (l & 15);
        int c = ch * 32 + (l >> 4) * 8 + j;
        wdef_ap[i] = (f16)w_def[o * 576 + c * 9 + kk];
    } else if (i < 55296) {
        int i2 = i - 36864;
        int j = i2 & 7, l = (i2 >> 3) & 63, m = (i2 >> 9) & 1, t = i2 >> 10;
        int kk = t >> 1, ch = t & 1;
        int o = m * 16 + (l & 15);
        int c = ch * 32 + (l >> 4) * 8 + j;
        woff_ap[i2] = (f16)((o < 18) ? w_off[o * 576 + c * 9 + kk] : 0.f);
    }
}

__global__ void k_prep(const float* __restrict__ w_off,
                       const float* __restrict__ w_def,
                       f16* __restrict__ wdef_ap,
                       f16* __restrict__ woff_ap) {
    prep_elem(blockIdx.x * 256 + threadIdx.x, w_off, w_def, wdef_ap, woff_ap);
}

// NCHW f32 -> NHWC f16 for all 4 batches, plus weight prep (merged launch).
__global__ void k_xprep(const float* __restrict__ x, f16* __restrict__ xt,
                        const float* __restrict__ w_off,
                        const float* __restrict__ w_def,
                        f16* __restrict__ wdef_ap,
                        f16* __restrict__ woff_ap) {
    int p = blockIdx.x * 256 + threadIdx.x;
    prep_elem(p, w_off, w_def, wdef_ap, woff_ap);
    int b = p >> 14, hw = p & 16383;
    const float* xb = x + (size_t)b * 64 * HWB + hw;
    f16x8 r[8];
    #pragma unroll
    for (int c = 0; c < 64; ++c) r[c >> 3][c & 7] = (f16)xb[(size_t)c * HWB];
    f16* ob = xt + (size_t)p * 64;
    #pragma unroll
    for (int q = 0; q < 8; ++q) *(f16x8*)(ob + q * 8) = r[q];
}

// NCHW f32 (slice) -> NHWC f16 (fallback path, per batch).
__global__ void k_xpose(const float* __restrict__ x, f16* __restrict__ xt) {
    int p = blockIdx.x * 256 + threadIdx.x;
    const float* xb = x + p;
    f16x8 r[8];
    #pragma unroll
    for (int c = 0; c < 64; ++c) r[c >> 3][c & 7] = (f16)xb[(size_t)c * HWB];
    f16* ob = xt + (size_t)p * 64;
    #pragma unroll
    for (int q = 0; q < 8; ++q) *(f16x8*)(ob + q * 8) = r[q];
}

// Block: 256 thr = 4 waves = 2 px-groups(16px) x 2 ch-halves; 32 px/block.
// Structure (2 barriers total):
//   stage band (issue-early) || phase0 from GLOBAL (redundant full-K/wave)
//   -> barrier -> phase1: preloop (all 9 kk addr+weights into regs), then
//   gathers+MFMA; red partial writes (separate buffer) -> barrier ->
//   balanced finalize (chh0 writes o0-31, chh1 writes o32-63).
__launch_bounds__(256, 4)
__global__ void k_fused(const f16* __restrict__ xt,      // NHWC f16 slice
                        const f16* __restrict__ woff_ap,
                        const float* __restrict__ b_off,
                        const f16* __restrict__ wdef_ap,
                        const float* __restrict__ b_def,
                        float* __restrict__ out, int bstart) {
    __shared__ __align__(16) char band[6 * 37 * 128];    // 28416 B
    __shared__ float offsm[18 * 33];                     // 2376 B
    __shared__ float red[64 * 33];                       // 8448 B

    int nwg = gridDim.x;
    int bid = blockIdx.x;
    int sb = (bid & 7) * (nwg >> 3) + (bid >> 3);        // bijective XCD swizzle
    int bl = sb >> 9, h = (sb >> 2) & 127, quarter = sb & 3;
    int b = bstart + bl;
    int s = quarter * 32;                                // block px start
    int tid = threadIdx.x;
    int lane = tid & 63, wv = tid >> 6;
    int pxg = wv & 1, chh = wv >> 1;
    int l15 = lane & 15, g = lane >> 4;
    int pxl = pxg * 16 + l15;

    const f16* xb = xt + (size_t)bl * HWB * 64;
    unsigned co = (unsigned)((chh * 4 + g) * 16);

    // ---------------- stage 6-row band (issue first) ----------------
    for (int i = tid; i < 6 * 37 * 8; i += 256) {
        int gg = i & 7, cell = (i >> 3) % 37, r = (i >> 3) / 37;
        int y = min(max(h - 2 + r, 0), 127);
        int xg = min(max(s - 2 + cell, 0), 127);
        f16x8 v = *(const f16x8*)(xb + (size_t)((y * 128 + xg) * 64 + gg * 8));
        int cc = gg ^ (cell & 7);
        *(f16x8*)(band + (r * 37 + cell) * 128 + cc * 16) = v;
    }

    // ------ phase 0: offset conv from GLOBAL, full K (redundant/wave) ------
    f32x4 oacc[2];
    {
        f32x4 z = {0.f, 0.f, 0.f, 0.f};
        oacc[0] = z; oacc[1] = z;
    }
    f16x8 zb = {};
    #pragma unroll
    for (int kk = 0; kk < 9; ++kk) {
        int ky = kk / 3 - 1, kx = kk - (kk / 3) * 3 - 1;
        int yy = h + ky, xx = s + pxl + kx;
        bool valid = ((unsigned)yy < 128u) && ((unsigned)xx < 128u);
        int yyc = min(max(yy, 0), 127), xxc = min(max(xx, 0), 127);
        unsigned ab = (unsigned)((yyc * 128 + xxc) * 64 + g * 8);
        #pragma unroll
        for (int hf = 0; hf < 2; ++hf) {
            int t = kk * 2 + hf;
            f16x8 B = *(const f16x8*)(xb + ab + (unsigned)(hf * 32));
            B = valid ? B : zb;
            #pragma unroll
            for (int m = 0; m < 2; ++m) {
                f16x8 A = *(const f16x8*)(woff_ap + ((size_t)(t * 2 + m) * 64 + lane) * 8);
                oacc[m] = __builtin_amdgcn_mfma_f32_16x16x32_f16(A, B, oacc[m], 0, 0, 0);
            }
        }
    }
    if (chh == 0) {
        #pragma unroll
        for (int m = 0; m < 2; ++m)
            #pragma unroll
            for (int r = 0; r < 4; ++r) {
                int o = m * 16 + g * 4 + r;
                if (o < 18) {
                    float v = oacc[m][r] + b_off[o];
                    offsm[o * 33 + pxl] = fminf(fmaxf(v, -1.f), 1.f);
                }
            }
    }
    __syncthreads();   // staging writes + offsm visible

    // ------ phase 1 preloop: all bilinear weights + LDS addrs into regs ----
    f16x4 wq[9];
    unsigned a0[9], a1[9], a2[9], a3[9];
    #pragma unroll
    for (int kk = 0; kk < 9; ++kk) {
        float dy = offsm[(2 * kk) * 33 + pxl];
        float dx = offsm[(2 * kk + 1) * 33 + pxl];
        int ky = kk / 3 - 1, kx = kk - (kk / 3) * 3 - 1;
        float py = (float)(h + ky) + dy;
        float pxf = (float)(s + pxl + kx) + dx;
        float y0f = floorf(py), x0f = floorf(pxf);
        float ly = py - y0f, lx = pxf - x0f;
        int y0 = (int)y0f, x0 = (int)x0f;
        float vy0 = ((unsigned)y0 < 128u) ? 1.f : 0.f;
        float vy1 = ((unsigned)(y0 + 1) < 128u) ? 1.f : 0.f;
        float vx0 = ((unsigned)x0 < 128u) ? 1.f : 0.f;
        float vx1 = ((unsigned)(x0 + 1) < 128u) ? 1.f : 0.f;
        wq[kk][0] = (f16)((1.f - ly) * (1.f - lx) * vy0 * vx0);
        wq[kk][1] = (f16)((1.f - ly) * lx * vy0 * vx1);
        wq[kk][2] = (f16)(ly * (1.f - lx) * vy1 * vx0);
        wq[kk][3] = (f16)(ly * lx * vy1 * vx1);
        int yc0 = min(max(y0, 0), 127), yc1 = min(max(y0 + 1, 0), 127);
        int xc0 = min(max(x0, 0), 127), xc1 = min(max(x0 + 1, 0), 127);
        int ry0 = yc0 - (h - 2), ry1 = yc1 - (h - 2);
        int cx0 = xc0 - (s - 2), cx1 = xc1 - (s - 2);
        unsigned s0 = co ^ (((unsigned)cx0 & 7u) << 4);
        unsigned s1 = co ^ (((unsigned)cx1 & 7u) << 4);
        a0[kk] = (unsigned)((ry0 * 37 + cx0) * 128) + s0;
        a1[kk] = (unsigned)((ry0 * 37 + cx1) * 128) + s1;
        a2[kk] = (unsigned)((ry1 * 37 + cx0) * 128) + s0;
        a3[kk] = (unsigned)((ry1 * 37 + cx1) * 128) + s1;
    }

    // ------ phase 1 main: gathers (addresses ready) -> interp -> MFMA ------
    f32x4 acc[4];
    {
        f32x4 z = {0.f, 0.f, 0.f, 0.f};
        acc[0] = z; acc[1] = z; acc[2] = z; acc[3] = z;
    }
    #pragma unroll
    for (int kk = 0; kk < 9; ++kk) {
        f16x8 c00 = *(const f16x8*)(band + a0[kk]);
        f16x8 c01 = *(const f16x8*)(band + a1[kk]);
        f16x8 c10 = *(const f16x8*)(band + a2[kk]);
        f16x8 c11 = *(const f16x8*)(band + a3[kk]);
        f16x8 B = c00 * wq[kk][0] + c01 * wq[kk][1] +
                  c10 * wq[kk][2] + c11 * wq[kk][3];
        int t = kk * 2 + chh;
        #pragma unroll
        for (int m = 0; m < 4; ++m) {
            f16x8 A = *(const f16x8*)(wdef_ap + ((size_t)(t * 4 + m) * 64 + lane) * 8);
            acc[m] = __builtin_amdgcn_mfma_f32_16x16x32_f16(A, B, acc[m], 0, 0, 0);
        }
    }

    // ------ balanced epilogue: each wave finalizes half the o-range --------
    int mw = chh ? 0 : 2;                  // m-pair this wave WRITES as partial
    #pragma unroll
    for (int mi = 0; mi < 2; ++mi) {
        int m = mw + mi;
        #pragma unroll
        for (int r = 0; r < 4; ++r) {
            int o = m * 16 + g * 4 + r;
            red[o * 33 + pxl] = acc[m][r];
        }
    }
    __syncthreads();
    int mo = chh ? 2 : 0;                  // m-pair this wave FINALIZES
    #pragma unroll
    for (int mi = 0; mi < 2; ++mi) {
        int m = mo + mi;
        #pragma unroll
        for (int r = 0; r < 4; ++r) {
            int o = m * 16 + g * 4 + r;
            float v = acc[m][r] + red[o * 33 + pxl] + b_def[o];
            out[(size_t)(b * 64 + o) * HWB + h * 128 + s + pxl] = v;
        }
    }
}

extern "C" void kernel_launch(void* const* d_in, const int* in_sizes, int n_in,
                              void* d_out, int out_size, void* d_ws, size_t ws_size,
                              hipStream_t stream) {
    const float* x     = (const float*)d_in[0];
    const float* w_off = (const float*)d_in[1];
    const float* b_off = (const float*)d_in[2];
    const float* w_def = (const float*)d_in[3];
    const float* b_def = (const float*)d_in[4];
    float* out = (float*)d_out;

    char* wsb = (char*)d_ws;
    f16* wdef_ap = (f16*)wsb;                    // 73728 B
    f16* woff_ap = (f16*)(wsb + 73728);          // 36864 B
    f16* xt      = (f16*)(wsb + 110592);         // NHWC f16

    if (ws_size >= (size_t)110592 + 8388608) {
        // single shot: prep + all-batch transpose merged, then fused kernel
        k_xprep<<<256, 256, 0, stream>>>(x, xt, w_off, w_def, wdef_ap, woff_ap);
        k_fused<<<2048, 256, 0, stream>>>(xt, woff_ap, b_off, wdef_ap, b_def, out, 0);
    } else {
        // batch-sliced fallback (2.1 MB slice, stream-ordered)
        k_prep<<<216, 256, 0, stream>>>(w_off, w_def, wdef_ap, woff_ap);
        for (int b = 0; b < 4; ++b) {
            k_xpose<<<64, 256, 0, stream>>>(x + (size_t)b * 64 * HWB, xt);
            k_fused<<<512, 256, 0, stream>>>(xt, woff_ap, b_off, wdef_ap, b_def, out, b);
        }
    }
}

// Round 11
// 39.513 us; speedup vs baseline: 1.5031x; 1.5031x over previous
//
#include <hip/hip_runtime.h>

typedef _Float16 f16;
typedef __attribute__((ext_vector_type(8))) _Float16 f16x8;
typedef __attribute__((ext_vector_type(4))) _Float16 f16x4;
typedef __attribute__((ext_vector_type(4))) float f32x4;

#define HWB 16384

// K layout (both GEMMs): k = kk*64 + c, 18 k-steps of 32 (ch-half in {0,1}).
// A-frag packs: lane l of k-step t, M-tile m holds W[o = m*16 + (l&15)]
//               [c = (t&1)*32 + (l>>4)*8 + j], kk = t>>1.
// wdef_ap: [t(18)][m(4)][lane(64)][j(8)] f16 = 73728 B
// woff_ap: [t(18)][m(2)][lane(64)][j(8)] f16 = 36864 B (o>=18 zero)

__device__ __forceinline__ void prep_elem(int i,
                                          const float* __restrict__ w_off,
                                          const float* __restrict__ w_def,
                                          f16* __restrict__ wdef_ap,
                                          f16* __restrict__ woff_ap) {
    if (i < 36864) {
        int j = i & 7, l = (i >> 3) & 63, m = (i >> 9) & 3, t = i >> 11;
        int kk = t >> 1, ch = t & 1;
        int o = m * 16 + (l & 15);
        int c = ch * 32 + (l >> 4) * 8 + j;
        wdef_ap[i] = (f16)w_def[o * 576 + c * 9 + kk];
    } else if (i < 55296) {
        int i2 = i - 36864;
        int j = i2 & 7, l = (i2 >> 3) & 63, m = (i2 >> 9) & 1, t = i2 >> 10;
        int kk = t >> 1, ch = t & 1;
        int o = m * 16 + (l & 15);
        int c = ch * 32 + (l >> 4) * 8 + j;
        woff_ap[i2] = (f16)((o < 18) ? w_off[o * 576 + c * 9 + kk] : 0.f);
    }
}

__global__ void k_prep(const float* __restrict__ w_off,
                       const float* __restrict__ w_def,
                       f16* __restrict__ wdef_ap,
                       f16* __restrict__ woff_ap) {
    prep_elem(blockIdx.x * 256 + threadIdx.x, w_off, w_def, wdef_ap, woff_ap);
}

// NCHW f32 -> NHWC f16 for all 4 batches, plus weight prep (merged launch).
__global__ void k_xprep(const float* __restrict__ x, f16* __restrict__ xt,
                        const float* __restrict__ w_off,
                        const float* __restrict__ w_def,
                        f16* __restrict__ wdef_ap,
                        f16* __restrict__ woff_ap) {
    int p = blockIdx.x * 256 + threadIdx.x;
    prep_elem(p, w_off, w_def, wdef_ap, woff_ap);
    int b = p >> 14, hw = p & 16383;
    const float* xb = x + (size_t)b * 64 * HWB + hw;
    f16x8 r[8];
    #pragma unroll
    for (int c = 0; c < 64; ++c) r[c >> 3][c & 7] = (f16)xb[(size_t)c * HWB];
    f16* ob = xt + (size_t)p * 64;
    #pragma unroll
    for (int q = 0; q < 8; ++q) *(f16x8*)(ob + q * 8) = r[q];
}

// NCHW f32 (slice) -> NHWC f16 (fallback path, per batch).
__global__ void k_xpose(const float* __restrict__ x, f16* __restrict__ xt) {
    int p = blockIdx.x * 256 + threadIdx.x;
    const float* xb = x + p;
    f16x8 r[8];
    #pragma unroll
    for (int c = 0; c < 64; ++c) r[c >> 3][c & 7] = (f16)xb[(size_t)c * HWB];
    f16* ob = xt + (size_t)p * 64;
    #pragma unroll
    for (int q = 0; q < 8; ++q) *(f16x8*)(ob + q * 8) = r[q];
}

// Block: 256 thr = 4 waves = 2 px-groups x 2 ch-halves; 32 px per block.
// Round-8 structure (band-staged phase 0, conflict-free red1 epilogue)
// + phase-1 issue-early preloop (all 9 kk bilinear weights + 36 LDS addrs
// computed into registers before any gather -> ds_read_b128s pipeline).
__launch_bounds__(256, 4)
__global__ void k_fused(const f16* __restrict__ xt,      // NHWC f16 slice
                        const f16* __restrict__ woff_ap,
                        const float* __restrict__ b_off,
                        const f16* __restrict__ wdef_ap,
                        const float* __restrict__ b_def,
                        float* __restrict__ out, int bstart) {
    __shared__ __align__(16) char band[6 * 40 * 128];    // 30720 B
    __shared__ float offsm[18 * 33];
    __shared__ float red0[8 * 128];
    float* red1 = (float*)band;                          // aliased after phase 1

    int nwg = gridDim.x;
    int bid = blockIdx.x;
    int sb = (bid & 7) * (nwg >> 3) + (bid >> 3);        // bijective XCD swizzle
    int bl = sb >> 9, h = (sb >> 2) & 127, quarter = sb & 3;
    int b = bstart + bl;
    int s = quarter * 32;                                // block px start
    int tid = threadIdx.x;
    int lane = tid & 63, wv = tid >> 6;
    int pxg = wv & 1, chh = wv >> 1;
    int l15 = lane & 15, g = lane >> 4;
    int pxl = pxg * 16 + l15;
    int pxb = s + pxl;
    int rlane = pxg * 64 + lane;

    const f16* xb = xt + (size_t)bl * HWB * 64;
    unsigned co = (unsigned)((chh * 4 + g) * 16);        // chunk offset pre-XOR

    // ---------------- stage 6-row band: rows h-2..h+3, cells s-2..s+34 ----
    for (int i = tid; i < 6 * 37 * 8; i += 256) {
        int gg = i & 7, cell = (i >> 3) % 37, r = (i >> 3) / 37;
        int y = min(max(h - 2 + r, 0), 127);
        int xg = min(max(s - 2 + cell, 0), 127);
        f16x8 v = *(const f16x8*)(xb + (size_t)((y * 128 + xg) * 64 + gg * 8));
        int cc = gg ^ (cell & 7);
        *(f16x8*)(band + (r * 40 + cell) * 128 + cc * 16) = v;
    }
    __syncthreads();

    // ---------------- phase 0: 3x3 offset conv (partial over ch-half) ----
    f32x4 oacc[2];
    {
        f32x4 z = {0.f, 0.f, 0.f, 0.f};
        oacc[0] = z; oacc[1] = z;
    }
    f16x8 zb = {};
    #pragma unroll
    for (int kk = 0; kk < 9; ++kk) {
        int ky = kk / 3 - 1, kx = kk - (kk / 3) * 3 - 1;
        int yy = h + ky, xx = pxb + kx;
        bool valid = ((unsigned)yy < 128u) && ((unsigned)xx < 128u);
        int ry = min(max(yy, 0), 127) - (h - 2);
        int cx = min(max(xx, 0), 127) - (s - 2);
        f16x8 B = *(const f16x8*)(band + (ry * 40 + cx) * 128 +
                                  (co ^ (((unsigned)cx & 7u) << 4)));
        B = valid ? B : zb;
        int t = kk * 2 + chh;
        #pragma unroll
        for (int m = 0; m < 2; ++m) {
            f16x8 A = *(const f16x8*)(woff_ap + ((size_t)(t * 2 + m) * 64 + lane) * 8);
            oacc[m] = __builtin_amdgcn_mfma_f32_16x16x32_f16(A, B, oacc[m], 0, 0, 0);
        }
    }
    if (chh == 1) {
        #pragma unroll
        for (int m = 0; m < 2; ++m)
            #pragma unroll
            for (int r = 0; r < 4; ++r) red0[(m * 4 + r) * 128 + rlane] = oacc[m][r];
    }
    __syncthreads();
    if (chh == 0) {
        #pragma unroll
        for (int m = 0; m < 2; ++m)
            #pragma unroll
            for (int r = 0; r < 4; ++r) {
                int o = m * 16 + g * 4 + r;
                if (o < 18) {
                    float v = oacc[m][r] + red0[(m * 4 + r) * 128 + rlane] + b_off[o];
                    offsm[o * 33 + pxl] = fminf(fmaxf(v, -1.f), 1.f);
                }
            }
    }
    __syncthreads();

    // ------ phase 1 preloop: all bilinear weights + LDS addrs into regs ----
    f16x4 wq[9];
    unsigned a0[9], a1[9], a2[9], a3[9];
    #pragma unroll
    for (int kk = 0; kk < 9; ++kk) {
        float dy = offsm[(2 * kk) * 33 + pxl];
        float dx = offsm[(2 * kk + 1) * 33 + pxl];
        int ky = kk / 3 - 1, kx = kk - (kk / 3) * 3 - 1;
        float py = (float)(h + ky) + dy;
        float pxf = (float)(pxb + kx) + dx;
        float y0f = floorf(py), x0f = floorf(pxf);
        float ly = py - y0f, lx = pxf - x0f;
        int y0 = (int)y0f, x0 = (int)x0f;
        float vy0 = ((unsigned)y0 < 128u) ? 1.f : 0.f;
        float vy1 = ((unsigned)(y0 + 1) < 128u) ? 1.f : 0.f;
        float vx0 = ((unsigned)x0 < 128u) ? 1.f : 0.f;
        float vx1 = ((unsigned)(x0 + 1) < 128u) ? 1.f : 0.f;
        wq[kk][0] = (f16)((1.f - ly) * (1.f - lx) * vy0 * vx0);
        wq[kk][1] = (f16)((1.f - ly) * lx * vy0 * vx1);
        wq[kk][2] = (f16)(ly * (1.f - lx) * vy1 * vx0);
        wq[kk][3] = (f16)(ly * lx * vy1 * vx1);
        int yc0 = min(max(y0, 0), 127), yc1 = min(max(y0 + 1, 0), 127);
        int xc0 = min(max(x0, 0), 127), xc1 = min(max(x0 + 1, 0), 127);
        int ry0 = yc0 - (h - 2), ry1 = yc1 - (h - 2);
        int cx0 = xc0 - (s - 2), cx1 = xc1 - (s - 2);
        unsigned s0 = co ^ (((unsigned)cx0 & 7u) << 4);
        unsigned s1 = co ^ (((unsigned)cx1 & 7u) << 4);
        a0[kk] = (unsigned)((ry0 * 40 + cx0) * 128) + s0;
        a1[kk] = (unsigned)((ry0 * 40 + cx1) * 128) + s1;
        a2[kk] = (unsigned)((ry1 * 40 + cx0) * 128) + s0;
        a3[kk] = (unsigned)((ry1 * 40 + cx1) * 128) + s1;
    }

    // ------ phase 1 main: gathers (addresses ready) -> interp -> MFMA ------
    f32x4 acc[4];
    {
        f32x4 z = {0.f, 0.f, 0.f, 0.f};
        acc[0] = z; acc[1] = z; acc[2] = z; acc[3] = z;
    }
    #pragma unroll
    for (int kk = 0; kk < 9; ++kk) {
        f16x8 c00 = *(const f16x8*)(band + a0[kk]);
        f16x8 c01 = *(const f16x8*)(band + a1[kk]);
        f16x8 c10 = *(const f16x8*)(band + a2[kk]);
        f16x8 c11 = *(const f16x8*)(band + a3[kk]);
        f16x8 B = c00 * wq[kk][0] + c01 * wq[kk][1] +
                  c10 * wq[kk][2] + c11 * wq[kk][3];
        int t = kk * 2 + chh;
        #pragma unroll
        for (int m = 0; m < 4; ++m) {
            f16x8 A = *(const f16x8*)(wdef_ap + ((size_t)(t * 4 + m) * 64 + lane) * 8);
            acc[m] = __builtin_amdgcn_mfma_f32_16x16x32_f16(A, B, acc[m], 0, 0, 0);
        }
    }

    __syncthreads();                                   // band reads done -> red1 safe
    if (chh == 1) {
        #pragma unroll
        for (int m = 0; m < 4; ++m)
            #pragma unroll
            for (int r = 0; r < 4; ++r) red1[(m * 4 + r) * 128 + rlane] = acc[m][r];
    }
    __syncthreads();
    if (chh == 0) {
        #pragma unroll
        for (int m = 0; m < 4; ++m)
            #pragma unroll
            for (int r = 0; r < 4; ++r) {
                int o = m * 16 + g * 4 + r;
                float v = acc[m][r] + red1[(m * 4 + r) * 128 + rlane] + b_def[o];
                out[(size_t)(b * 64 + o) * HWB + h * 128 + pxb] = v;
            }
    }
}

extern "C" void kernel_launch(void* const* d_in, const int* in_sizes, int n_in,
                              void* d_out, int out_size, void* d_ws, size_t ws_size,
                              hipStream_t stream) {
    const float* x     = (const float*)d_in[0];
    const float* w_off = (const float*)d_in[1];
    const float* b_off = (const float*)d_in[2];
    const float* w_def = (const float*)d_in[3];
    const float* b_def = (const float*)d_in[4];
    float* out = (float*)d_out;

    char* wsb = (char*)d_ws;
    f16* wdef_ap = (f16*)wsb;                    // 73728 B
    f16* woff_ap = (f16*)(wsb + 73728);          // 36864 B
    f16* xt      = (f16*)(wsb + 110592);         // NHWC f16

    if (ws_size >= (size_t)110592 + 8388608) {
        // single shot: prep + all-batch transpose merged, then fused kernel
        k_xprep<<<256, 256, 0, stream>>>(x, xt, w_off, w_def, wdef_ap, woff_ap);
        k_fused<<<2048, 256, 0, stream>>>(xt, woff_ap, b_off, wdef_ap, b_def, out, 0);
    } else {
        // batch-sliced fallback (2.1 MB slice, stream-ordered)
        k_prep<<<216, 256, 0, stream>>>(w_off, w_def, wdef_ap, woff_ap);
        for (int b = 0; b < 4; ++b) {
            k_xpose<<<64, 256, 0, stream>>>(x + (size_t)b * 64 * HWB, xt);
            k_fused<<<512, 256, 0, stream>>>(xt, woff_ap, b_off, wdef_ap, b_def, out, b);
        }
    }
}

// Round 12
// 37.408 us; speedup vs baseline: 1.5877x; 1.0563x over previous
//
#include <hip/hip_runtime.h>

typedef _Float16 f16;
typedef __attribute__((ext_vector_type(8))) _Float16 f16x8;
typedef __attribute__((ext_vector_type(4))) _Float16 f16x4;
typedef __attribute__((ext_vector_type(4))) float f32x4;

#define HWB 16384

// K layout (both GEMMs): k = kk*64 + c, 18 k-steps of 32 (ch-half in {0,1}).
// A-frag packs: lane l of k-step t, M-tile m holds W[o = m*16 + (l&15)]
//               [c = (t&1)*32 + (l>>4)*8 + j], kk = t>>1.
// wdef_ap: [t(18)][m(4)][lane(64)][j(8)] f16 = 73728 B
// woff_ap: [t(18)][m(2)][lane(64)][j(8)] f16 = 36864 B (o>=18 zero)

__device__ __forceinline__ void prep_elem(int i,
                                          const float* __restrict__ w_off,
                                          const float* __restrict__ w_def,
                                          f16* __restrict__ wdef_ap,
                                          f16* __restrict__ woff_ap) {
    if (i < 36864) {
        int j = i & 7, l = (i >> 3) & 63, m = (i >> 9) & 3, t = i >> 11;
        int kk = t >> 1, ch = t & 1;
        int o = m * 16 + (l & 15);
        int c = ch * 32 + (l >> 4) * 8 + j;
        wdef_ap[i] = (f16)w_def[o * 576 + c * 9 + kk];
    } else if (i < 55296) {
        int i2 = i - 36864;
        int j = i2 & 7, l = (i2 >> 3) & 63, m = (i2 >> 9) & 1, t = i2 >> 10;
        int kk = t >> 1, ch = t & 1;
        int o = m * 16 + (l & 15);
        int c = ch * 32 + (l >> 4) * 8 + j;
        woff_ap[i2] = (f16)((o < 18) ? w_off[o * 576 + c * 9 + kk] : 0.f);
    }
}

__global__ void k_prep(const float* __restrict__ w_off,
                       const float* __restrict__ w_def,
                       f16* __restrict__ wdef_ap,
                       f16* __restrict__ woff_ap) {
    prep_elem(blockIdx.x * 256 + threadIdx.x, w_off, w_def, wdef_ap, woff_ap);
}

// NCHW f32 -> NHWC f16 for all 4 batches, plus weight prep (merged launch).
__global__ void k_xprep(const float* __restrict__ x, f16* __restrict__ xt,
                        const float* __restrict__ w_off,
                        const float* __restrict__ w_def,
                        f16* __restrict__ wdef_ap,
                        f16* __restrict__ woff_ap) {
    int p = blockIdx.x * 256 + threadIdx.x;
    prep_elem(p, w_off, w_def, wdef_ap, woff_ap);
    int b = p >> 14, hw = p & 16383;
    const float* xb = x + (size_t)b * 64 * HWB + hw;
    f16x8 r[8];
    #pragma unroll
    for (int c = 0; c < 64; ++c) r[c >> 3][c & 7] = (f16)xb[(size_t)c * HWB];
    f16* ob = xt + (size_t)p * 64;
    #pragma unroll
    for (int q = 0; q < 8; ++q) *(f16x8*)(ob + q * 8) = r[q];
}

// NCHW f32 (slice) -> NHWC f16 (fallback path, per batch).
__global__ void k_xpose(const float* __restrict__ x, f16* __restrict__ xt) {
    int p = blockIdx.x * 256 + threadIdx.x;
    const float* xb = x + p;
    f16x8 r[8];
    #pragma unroll
    for (int c = 0; c < 64; ++c) r[c >> 3][c & 7] = (f16)xb[(size_t)c * HWB];
    f16* ob = xt + (size_t)p * 64;
    #pragma unroll
    for (int q = 0; q < 8; ++q) *(f16x8*)(ob + q * 8) = r[q];
}

// Block: 256 thr = 4 waves = 2 px-groups x 2 ch-halves; 32 px per block.
// Round-11 structure; staging now via global_load_lds (direct-to-LDS DMA):
// linear LDS dest (uniform base + lane*16) + pre-swizzled per-lane global
// source (gg = cc ^ (cell&7)); XOR is an involution so read-side swizzle
// is unchanged. 30 wave-uniform groups (8 cells x 8 chunks each; seg 4 is a
// 40-lane exec-masked tail), gid = wv + 4k.
__launch_bounds__(256, 4)
__global__ void k_fused(const f16* __restrict__ xt,      // NHWC f16 slice
                        const f16* __restrict__ woff_ap,
                        const float* __restrict__ b_off,
                        const f16* __restrict__ wdef_ap,
                        const float* __restrict__ b_def,
                        float* __restrict__ out, int bstart) {
    __shared__ __align__(16) char band[6 * 40 * 128];    // 30720 B
    __shared__ float offsm[18 * 33];
    __shared__ float red0[8 * 128];
    float* red1 = (float*)band;                          // aliased after phase 1

    int nwg = gridDim.x;
    int bid = blockIdx.x;
    int sb = (bid & 7) * (nwg >> 3) + (bid >> 3);        // bijective XCD swizzle
    int bl = sb >> 9, h = (sb >> 2) & 127, quarter = sb & 3;
    int b = bstart + bl;
    int s = quarter * 32;                                // block px start
    int tid = threadIdx.x;
    int lane = tid & 63, wv = tid >> 6;
    int pxg = wv & 1, chh = wv >> 1;
    int l15 = lane & 15, g = lane >> 4;
    int pxl = pxg * 16 + l15;
    int pxb = s + pxl;
    int rlane = pxg * 64 + lane;

    const f16* xb = xt + (size_t)bl * HWB * 64;
    unsigned co = (unsigned)((chh * 4 + g) * 16);        // chunk offset pre-XOR

    // ---------------- stage 6-row band via global_load_lds ----------------
    {
        int cell_lo = lane >> 3, cc = lane & 7;
        for (int gid = wv; gid < 30; gid += 4) {
            int r = gid / 5, seg = gid - (gid / 5) * 5;
            int cell0 = seg * 8;
            int cell = cell0 + cell_lo;
            int y = min(max(h - 2 + r, 0), 127);
            int xg = min(max(s - 2 + cell, 0), 127);
            int gg = cc ^ (cell & 7);
            const f16* gsrc = xb + (size_t)((y * 128 + xg) * 64 + gg * 8);
            char* ldst = band + (r * 40 + cell0) * 128;  // wave-uniform
            if (cell < 37)
                __builtin_amdgcn_global_load_lds(
                    (const __attribute__((address_space(1))) unsigned int*)gsrc,
                    (__attribute__((address_space(3))) unsigned int*)ldst,
                    16, 0, 0);
        }
    }
    __syncthreads();

    // ---------------- phase 0: 3x3 offset conv (partial over ch-half) ----
    f32x4 oacc[2];
    {
        f32x4 z = {0.f, 0.f, 0.f, 0.f};
        oacc[0] = z; oacc[1] = z;
    }
    f16x8 zb = {};
    #pragma unroll
    for (int kk = 0; kk < 9; ++kk) {
        int ky = kk / 3 - 1, kx = kk - (kk / 3) * 3 - 1;
        int yy = h + ky, xx = pxb + kx;
        bool valid = ((unsigned)yy < 128u) && ((unsigned)xx < 128u);
        int ry = min(max(yy, 0), 127) - (h - 2);
        int cx = min(max(xx, 0), 127) - (s - 2);
        f16x8 B = *(const f16x8*)(band + (ry * 40 + cx) * 128 +
                                  (co ^ (((unsigned)cx & 7u) << 4)));
        B = valid ? B : zb;
        int t = kk * 2 + chh;
        #pragma unroll
        for (int m = 0; m < 2; ++m) {
            f16x8 A = *(const f16x8*)(woff_ap + ((size_t)(t * 2 + m) * 64 + lane) * 8);
            oacc[m] = __builtin_amdgcn_mfma_f32_16x16x32_f16(A, B, oacc[m], 0, 0, 0);
        }
    }
    if (chh == 1) {
        #pragma unroll
        for (int m = 0; m < 2; ++m)
            #pragma unroll
            for (int r = 0; r < 4; ++r) red0[(m * 4 + r) * 128 + rlane] = oacc[m][r];
    }
    __syncthreads();
    if (chh == 0) {
        #pragma unroll
        for (int m = 0; m < 2; ++m)
            #pragma unroll
            for (int r = 0; r < 4; ++r) {
                int o = m * 16 + g * 4 + r;
                if (o < 18) {
                    float v = oacc[m][r] + red0[(m * 4 + r) * 128 + rlane] + b_off[o];
                    offsm[o * 33 + pxl] = fminf(fmaxf(v, -1.f), 1.f);
                }
            }
    }
    __syncthreads();

    // ------ phase 1 preloop: all bilinear weights + LDS addrs into regs ----
    f16x4 wq[9];
    unsigned a0[9], a1[9], a2[9], a3[9];
    #pragma unroll
    for (int kk = 0; kk < 9; ++kk) {
        float dy = offsm[(2 * kk) * 33 + pxl];
        float dx = offsm[(2 * kk + 1) * 33 + pxl];
        int ky = kk / 3 - 1, kx = kk - (kk / 3) * 3 - 1;
        float py = (float)(h + ky) + dy;
        float pxf = (float)(pxb + kx) + dx;
        float y0f = floorf(py), x0f = floorf(pxf);
        float ly = py - y0f, lx = pxf - x0f;
        int y0 = (int)y0f, x0 = (int)x0f;
        float vy0 = ((unsigned)y0 < 128u) ? 1.f : 0.f;
        float vy1 = ((unsigned)(y0 + 1) < 128u) ? 1.f : 0.f;
        float vx0 = ((unsigned)x0 < 128u) ? 1.f : 0.f;
        float vx1 = ((unsigned)(x0 + 1) < 128u) ? 1.f : 0.f;
        wq[kk][0] = (f16)((1.f - ly) * (1.f - lx) * vy0 * vx0);
        wq[kk][1] = (f16)((1.f - ly) * lx * vy0 * vx1);
        wq[kk][2] = (f16)(ly * (1.f - lx) * vy1 * vx0);
        wq[kk][3] = (f16)(ly * lx * vy1 * vx1);
        int yc0 = min(max(y0, 0), 127), yc1 = min(max(y0 + 1, 0), 127);
        int xc0 = min(max(x0, 0), 127), xc1 = min(max(x0 + 1, 0), 127);
        int ry0 = yc0 - (h - 2), ry1 = yc1 - (h - 2);
        int cx0 = xc0 - (s - 2), cx1 = xc1 - (s - 2);
        unsigned s0 = co ^ (((unsigned)cx0 & 7u) << 4);
        unsigned s1 = co ^ (((unsigned)cx1 & 7u) << 4);
        a0[kk] = (unsigned)((ry0 * 40 + cx0) * 128) + s0;
        a1[kk] = (unsigned)((ry0 * 40 + cx1) * 128) + s1;
        a2[kk] = (unsigned)((ry1 * 40 + cx0) * 128) + s0;
        a3[kk] = (unsigned)((ry1 * 40 + cx1) * 128) + s1;
    }

    // ------ phase 1 main: gathers (addresses ready) -> interp -> MFMA ------
    f32x4 acc[4];
    {
        f32x4 z = {0.f, 0.f, 0.f, 0.f};
        acc[0] = z; acc[1] = z; acc[2] = z; acc[3] = z;
    }
    #pragma unroll
    for (int kk = 0; kk < 9; ++kk) {
        f16x8 c00 = *(const f16x8*)(band + a0[kk]);
        f16x8 c01 = *(const f16x8*)(band + a1[kk]);
        f16x8 c10 = *(const f16x8*)(band + a2[kk]);
        f16x8 c11 = *(const f16x8*)(band + a3[kk]);
        f16x8 B = c00 * wq[kk][0] + c01 * wq[kk][1] +
                  c10 * wq[kk][2] + c11 * wq[kk][3];
        int t = kk * 2 + chh;
        #pragma unroll
        for (int m = 0; m < 4; ++m) {
            f16x8 A = *(const f16x8*)(wdef_ap + ((size_t)(t * 4 + m) * 64 + lane) * 8);
            acc[m] = __builtin_amdgcn_mfma_f32_16x16x32_f16(A, B, acc[m], 0, 0, 0);
        }
    }

    __syncthreads();                                   // band reads done -> red1 safe
    if (chh == 1) {
        #pragma unroll
        for (int m = 0; m < 4; ++m)
            #pragma unroll
            for (int r = 0; r < 4; ++r) red1[(m * 4 + r) * 128 + rlane] = acc[m][r];
    }
    __syncthreads();
    if (chh == 0) {
        #pragma unroll
        for (int m = 0; m < 4; ++m)
            #pragma unroll
            for (int r = 0; r < 4; ++r) {
                int o = m * 16 + g * 4 + r;
                float v = acc[m][r] + red1[(m * 4 + r) * 128 + rlane] + b_def[o];
                out[(size_t)(b * 64 + o) * HWB + h * 128 + pxb] = v;
            }
    }
}

extern "C" void kernel_launch(void* const* d_in, const int* in_sizes, int n_in,
                              void* d_out, int out_size, void* d_ws, size_t ws_size,
                              hipStream_t stream) {
    const float* x     = (const float*)d_in[0];
    const float* w_off = (const float*)d_in[1];
    const float* b_off = (const float*)d_in[2];
    const float* w_def = (const float*)d_in[3];
    const float* b_def = (const float*)d_in[4];
    float* out = (float*)d_out;

    char* wsb = (char*)d_ws;
    f16* wdef_ap = (f16*)wsb;                    // 73728 B
    f16* woff_ap = (f16*)(wsb + 73728);          // 36864 B
    f16* xt      = (f16*)(wsb + 110592);         // NHWC f16

    if (ws_size >= (size_t)110592 + 8388608) {
        // single shot: prep + all-batch transpose merged, then fused kernel
        k_xprep<<<256, 256, 0, stream>>>(x, xt, w_off, w_def, wdef_ap, woff_ap);
        k_fused<<<2048, 256, 0, stream>>>(xt, woff_ap, b_off, wdef_ap, b_def, out, 0);
    } else {
        // batch-sliced fallback (2.1 MB slice, stream-ordered)
        k_prep<<<216, 256, 0, stream>>>(w_off, w_def, wdef_ap, woff_ap);
        for (int b = 0; b < 4; ++b) {
            k_xpose<<<64, 256, 0, stream>>>(x + (size_t)b * 64 * HWB, xt);
            k_fused<<<512, 256, 0, stream>>>(xt, woff_ap, b_off, wdef_ap, b_def, out, b);
        }
    }
}

// Round 13
// 36.223 us; speedup vs baseline: 1.6397x; 1.0327x over previous
//
#include <hip/hip_runtime.h>

typedef _Float16 f16;
typedef __attribute__((ext_vector_type(8))) _Float16 f16x8;
typedef __attribute__((ext_vector_type(4))) _Float16 f16x4;
typedef __attribute__((ext_vector_type(16))) float f32x16;

#define HWB 16384

// K layout (both GEMMs): k-step = (kk, chq): kk in 0..8, chq = 16-ch quarter.
// 32x32x16 fragments. A-pack: lane l of step (kk,chq), m-tile holds
//   W[o = m*32 + (l&31)][c = chq*16 + (l>>5)*8 + j], j=0..7.
// wdef_ap: [kk(9)][chq(4)][m(2)][lane(64)][j(8)] f16 = 73728 B
// woff_ap: [kk(9)][chq(4)][lane(64)][j(8)]       f16 = 36864 B (o>=18 zero)
// C/D layout (guide, m74/m101): col = lane&31, row = (reg&3)+8*(reg>>2)+4*(lane>>5).

__device__ __forceinline__ void prep_elem(int i,
                                          const float* __restrict__ w_off,
                                          const float* __restrict__ w_def,
                                          f16* __restrict__ wdef_ap,
                                          f16* __restrict__ woff_ap) {
    if (i < 36864) {
        int j = i & 7, l = (i >> 3) & 63, m = (i >> 9) & 1;
        int chq = (i >> 10) & 3, kk = i >> 12;
        int o = m * 32 + (l & 31);
        int c = chq * 16 + (l >> 5) * 8 + j;
        wdef_ap[i] = (f16)w_def[o * 576 + c * 9 + kk];
    } else if (i < 55296) {
        int i2 = i - 36864;
        int j = i2 & 7, l = (i2 >> 3) & 63;
        int chq = (i2 >> 9) & 3, kk = i2 >> 11;
        int o = l & 31;
        int c = chq * 16 + (l >> 5) * 8 + j;
        woff_ap[i2] = (f16)((o < 18) ? w_off[o * 576 + c * 9 + kk] : 0.f);
    }
}

__global__ void k_prep(const float* __restrict__ w_off,
                       const float* __restrict__ w_def,
                       f16* __restrict__ wdef_ap,
                       f16* __restrict__ woff_ap) {
    prep_elem(blockIdx.x * 256 + threadIdx.x, w_off, w_def, wdef_ap, woff_ap);
}

// NCHW f32 -> NHWC f16 for all 4 batches, plus weight prep (merged launch).
__global__ void k_xprep(const float* __restrict__ x, f16* __restrict__ xt,
                        const float* __restrict__ w_off,
                        const float* __restrict__ w_def,
                        f16* __restrict__ wdef_ap,
                        f16* __restrict__ woff_ap) {
    int p = blockIdx.x * 256 + threadIdx.x;
    prep_elem(p, w_off, w_def, wdef_ap, woff_ap);
    int b = p >> 14, hw = p & 16383;
    const float* xb = x + (size_t)b * 64 * HWB + hw;
    f16x8 r[8];
    #pragma unroll
    for (int c = 0; c < 64; ++c) r[c >> 3][c & 7] = (f16)xb[(size_t)c * HWB];
    f16* ob = xt + (size_t)p * 64;
    #pragma unroll
    for (int q = 0; q < 8; ++q) *(f16x8*)(ob + q * 8) = r[q];
}

// NCHW f32 (slice) -> NHWC f16 (fallback path, per batch).
__global__ void k_xpose(const float* __restrict__ x, f16* __restrict__ xt) {
    int p = blockIdx.x * 256 + threadIdx.x;
    const float* xb = x + p;
    f16x8 r[8];
    #pragma unroll
    for (int c = 0; c < 64; ++c) r[c >> 3][c & 7] = (f16)xb[(size_t)c * HWB];
    f16* ob = xt + (size_t)p * 64;
    #pragma unroll
    for (int q = 0; q < 8; ++q) *(f16x8*)(ob + q * 8) = r[q];
}

// Block: 256 thr = 4 waves = 4 K-quarters (chq); 32 px per block.
// Wave lane: px = l&31, half = l>>5 -> channel octet chq*16 + half*8.
// Staging + preloop as round 12 (global_load_lds, XOR chunk swizzle).
// Phase 0: 1 m-tile of 32x32x16 per kk per wave; 4-way K-reduce (o<18
// trimmed partials) -> offsm. Phase 1: 2 m-tiles per kk per wave; 4-way
// K-reduce through LDS aliased onto the dead band; chq0 finalizes.
__launch_bounds__(256, 4)
__global__ void k_fused(const f16* __restrict__ xt,      // NHWC f16 slice
                        const f16* __restrict__ woff_ap,
                        const float* __restrict__ b_off,
                        const f16* __restrict__ wdef_ap,
                        const float* __restrict__ b_def,
                        float* __restrict__ out, int bstart) {
    __shared__ __align__(16) char band[6 * 40 * 128];    // 30720 B
    __shared__ float offsm[18 * 33];                     // 2376 B
    __shared__ float red0[3 * 594];                      // 7128 B (o<18)
    float* red1 = (float*)band;                          // [3][64][33] alias

    int nwg = gridDim.x;
    int bid = blockIdx.x;
    int sb = (bid & 7) * (nwg >> 3) + (bid >> 3);        // bijective XCD swizzle
    int bl = sb >> 9, h = (sb >> 2) & 127, quarter = sb & 3;
    int b = bstart + bl;
    int s = quarter * 32;                                // block px start
    int tid = threadIdx.x;
    int lane = tid & 63, chq = tid >> 6;
    int px = lane & 31, half = lane >> 5;
    int pxb = s + px;

    const f16* xb = xt + (size_t)bl * HWB * 64;
    unsigned co = (unsigned)((chq * 2 + half) * 16);     // chunk byte off pre-XOR

    // ---------------- stage 6-row band via global_load_lds ----------------
    {
        int cell_lo = lane >> 3, cc = lane & 7;
        for (int gid = chq; gid < 30; gid += 4) {
            int r = gid / 5, seg = gid - (gid / 5) * 5;
            int cell0 = seg * 8;
            int cell = cell0 + cell_lo;
            int y = min(max(h - 2 + r, 0), 127);
            int xg = min(max(s - 2 + cell, 0), 127);
            int gg = cc ^ (cell & 7);
            const f16* gsrc = xb + (size_t)((y * 128 + xg) * 64 + gg * 8);
            char* ldst = band + (r * 40 + cell0) * 128;  // wave-uniform
            if (cell < 37)
                __builtin_amdgcn_global_load_lds(
                    (const __attribute__((address_space(1))) unsigned int*)gsrc,
                    (__attribute__((address_space(3))) unsigned int*)ldst,
                    16, 0, 0);
        }
    }
    __syncthreads();

    // -------- phase 0: offset conv, one 32-tile, K-quarter per wave -------
    f32x16 oacc = {};
    f16x8 zb = {};
    #pragma unroll
    for (int kk = 0; kk < 9; ++kk) {
        int ky = kk / 3 - 1, kx = kk - (kk / 3) * 3 - 1;
        int yy = h + ky, xx = pxb + kx;
        bool valid = ((unsigned)yy < 128u) && ((unsigned)xx < 128u);
        int ry = min(max(yy, 0), 127) - (h - 2);
        int cx = min(max(xx, 0), 127) - (s - 2);
        f16x8 B = *(const f16x8*)(band + (ry * 40 + cx) * 128 +
                                  (co ^ (((unsigned)cx & 7u) << 4)));
        B = valid ? B : zb;
        f16x8 A = *(const f16x8*)(woff_ap + ((size_t)(kk * 4 + chq) * 64 + lane) * 8);
        oacc = __builtin_amdgcn_mfma_f32_32x32x16_f16(A, B, oacc, 0, 0, 0);
    }
    if (chq != 0) {
        #pragma unroll
        for (int reg = 0; reg < 16; ++reg) {
            int row = (reg & 3) + 8 * (reg >> 2) + 4 * half;
            if (row < 18) red0[(chq - 1) * 594 + row * 33 + px] = oacc[reg];
        }
    }
    __syncthreads();
    if (chq == 0) {
        #pragma unroll
        for (int reg = 0; reg < 16; ++reg) {
            int row = (reg & 3) + 8 * (reg >> 2) + 4 * half;
            if (row < 18) {
                float v = oacc[reg] + red0[row * 33 + px] +
                          red0[594 + row * 33 + px] + red0[1188 + row * 33 + px] +
                          b_off[row];
                offsm[row * 33 + px] = fminf(fmaxf(v, -1.f), 1.f);
            }
        }
    }
    __syncthreads();

    // ------ phase 1 preloop: all bilinear weights + LDS addrs into regs ----
    f16x4 wq[9];
    unsigned a0[9], a1[9], a2[9], a3[9];
    #pragma unroll
    for (int kk = 0; kk < 9; ++kk) {
        float dy = offsm[(2 * kk) * 33 + px];
        float dx = offsm[(2 * kk + 1) * 33 + px];
        int ky = kk / 3 - 1, kx = kk - (kk / 3) * 3 - 1;
        float py = (float)(h + ky) + dy;
        float pxf = (float)(pxb + kx) + dx;
        float y0f = floorf(py), x0f = floorf(pxf);
        float ly = py - y0f, lx = pxf - x0f;
        int y0 = (int)y0f, x0 = (int)x0f;
        float vy0 = ((unsigned)y0 < 128u) ? 1.f : 0.f;
        float vy1 = ((unsigned)(y0 + 1) < 128u) ? 1.f : 0.f;
        float vx0 = ((unsigned)x0 < 128u) ? 1.f : 0.f;
        float vx1 = ((unsigned)(x0 + 1) < 128u) ? 1.f : 0.f;
        wq[kk][0] = (f16)((1.f - ly) * (1.f - lx) * vy0 * vx0);
        wq[kk][1] = (f16)((1.f - ly) * lx * vy0 * vx1);
        wq[kk][2] = (f16)(ly * (1.f - lx) * vy1 * vx0);
        wq[kk][3] = (f16)(ly * lx * vy1 * vx1);
        int yc0 = min(max(y0, 0), 127), yc1 = min(max(y0 + 1, 0), 127);
        int xc0 = min(max(x0, 0), 127), xc1 = min(max(x0 + 1, 0), 127);
        int ry0 = yc0 - (h - 2), ry1 = yc1 - (h - 2);
        int cx0 = xc0 - (s - 2), cx1 = xc1 - (s - 2);
        unsigned s0 = co ^ (((unsigned)cx0 & 7u) << 4);
        unsigned s1 = co ^ (((unsigned)cx1 & 7u) << 4);
        a0[kk] = (unsigned)((ry0 * 40 + cx0) * 128) + s0;
        a1[kk] = (unsigned)((ry0 * 40 + cx1) * 128) + s1;
        a2[kk] = (unsigned)((ry1 * 40 + cx0) * 128) + s0;
        a3[kk] = (unsigned)((ry1 * 40 + cx1) * 128) + s1;
    }

    // ------ phase 1 main: gathers -> interp -> 2 MFMAs per kk -------------
    f32x16 acc0 = {}, acc1 = {};
    #pragma unroll
    for (int kk = 0; kk < 9; ++kk) {
        f16x8 c00 = *(const f16x8*)(band + a0[kk]);
        f16x8 c01 = *(const f16x8*)(band + a1[kk]);
        f16x8 c10 = *(const f16x8*)(band + a2[kk]);
        f16x8 c11 = *(const f16x8*)(band + a3[kk]);
        f16x8 B = c00 * wq[kk][0] + c01 * wq[kk][1] +
                  c10 * wq[kk][2] + c11 * wq[kk][3];
        size_t tb = (size_t)((kk * 4 + chq) * 2) * 64 * 8;
        f16x8 A0 = *(const f16x8*)(wdef_ap + tb + (size_t)lane * 8);
        f16x8 A1 = *(const f16x8*)(wdef_ap + tb + (size_t)(64 + lane) * 8);
        acc0 = __builtin_amdgcn_mfma_f32_32x32x16_f16(A0, B, acc0, 0, 0, 0);
        acc1 = __builtin_amdgcn_mfma_f32_32x32x16_f16(A1, B, acc1, 0, 0, 0);
    }

    __syncthreads();                  // band reads done -> red1 safe
    if (chq != 0) {
        #pragma unroll
        for (int m = 0; m < 2; ++m)
            #pragma unroll
            for (int reg = 0; reg < 16; ++reg) {
                int o = m * 32 + (reg & 3) + 8 * (reg >> 2) + 4 * half;
                float v = m ? acc1[reg] : acc0[reg];
                red1[(chq - 1) * 2112 + o * 33 + px] = v;
            }
    }
    __syncthreads();
    if (chq == 0) {
        #pragma unroll
        for (int m = 0; m < 2; ++m)
            #pragma unroll
            for (int reg = 0; reg < 16; ++reg) {
                int o = m * 32 + (reg & 3) + 8 * (reg >> 2) + 4 * half;
                float v = (m ? acc1[reg] : acc0[reg]) +
                          red1[o * 33 + px] + red1[2112 + o * 33 + px] +
                          red1[4224 + o * 33 + px] + b_def[o];
                out[(size_t)(b * 64 + o) * HWB + h * 128 + pxb] = v;
            }
    }
}

extern "C" void kernel_launch(void* const* d_in, const int* in_sizes, int n_in,
                              void* d_out, int out_size, void* d_ws, size_t ws_size,
                              hipStream_t stream) {
    const float* x     = (const float*)d_in[0];
    const float* w_off = (const float*)d_in[1];
    const float* b_off = (const float*)d_in[2];
    const float* w_def = (const float*)d_in[3];
    const float* b_def = (const float*)d_in[4];
    float* out = (float*)d_out;

    char* wsb = (char*)d_ws;
    f16* wdef_ap = (f16*)wsb;                    // 73728 B
    f16* woff_ap = (f16*)(wsb + 73728);          // 36864 B
    f16* xt      = (f16*)(wsb + 110592);         // NHWC f16

    if (ws_size >= (size_t)110592 + 8388608) {
        // single shot: prep + all-batch transpose merged, then fused kernel
        k_xprep<<<256, 256, 0, stream>>>(x, xt, w_off, w_def, wdef_ap, woff_ap);
        k_fused<<<2048, 256, 0, stream>>>(xt, woff_ap, b_off, wdef_ap, b_def, out, 0);
    } else {
        // batch-sliced fallback (2.1 MB slice, stream-ordered)
        k_prep<<<216, 256, 0, stream>>>(w_off, w_def, wdef_ap, woff_ap);
        for (int b = 0; b < 4; ++b) {
            k_xpose<<<64, 256, 0, stream>>>(x + (size_t)b * 64 * HWB, xt);
            k_fused<<<512, 256, 0, stream>>>(xt, woff_ap, b_off, wdef_ap, b_def, out, b);
        }
    }
}

// Round 14
// 34.237 us; speedup vs baseline: 1.7348x; 1.0580x over previous
//
#include <hip/hip_runtime.h>

typedef _Float16 f16;
typedef __attribute__((ext_vector_type(8))) _Float16 f16x8;
typedef __attribute__((ext_vector_type(4))) _Float16 f16x4;
typedef __attribute__((ext_vector_type(16))) float f32x16;
typedef __attribute__((ext_vector_type(4))) unsigned int u32x4;

#define HWB 16384

// K layout (both GEMMs): k-step = (kk, chq): kk in 0..8, chq = 16-ch quarter.
// 32x32x16 fragments. A-pack: lane l of step (kk,chq), m-tile holds
//   W[o = m*32 + (l&31)][c = chq*16 + (l>>5)*8 + j], j=0..7.
// wdef_ap: [kk(9)][chq(4)][m(2)][lane(64)][j(8)] f16 = 73728 B
// woff_ap: [kk(9)][chq(4)][lane(64)][j(8)]       f16 = 36864 B (o>=18 zero)
// C/D layout (guide, m74/m101): col = lane&31, row = (reg&3)+8*(reg>>2)+4*(lane>>5).

__device__ __forceinline__ void prep_elem(int i,
                                          const float* __restrict__ w_off,
                                          const float* __restrict__ w_def,
                                          f16* __restrict__ wdef_ap,
                                          f16* __restrict__ woff_ap) {
    if (i < 36864) {
        int j = i & 7, l = (i >> 3) & 63, m = (i >> 9) & 1;
        int chq = (i >> 10) & 3, kk = i >> 12;
        int o = m * 32 + (l & 31);
        int c = chq * 16 + (l >> 5) * 8 + j;
        wdef_ap[i] = (f16)w_def[o * 576 + c * 9 + kk];
    } else if (i < 55296) {
        int i2 = i - 36864;
        int j = i2 & 7, l = (i2 >> 3) & 63;
        int chq = (i2 >> 9) & 3, kk = i2 >> 11;
        int o = l & 31;
        int c = chq * 16 + (l >> 5) * 8 + j;
        woff_ap[i2] = (f16)((o < 18) ? w_off[o * 576 + c * 9 + kk] : 0.f);
    }
}

__global__ void k_prep(const float* __restrict__ w_off,
                       const float* __restrict__ w_def,
                       f16* __restrict__ wdef_ap,
                       f16* __restrict__ woff_ap) {
    prep_elem(blockIdx.x * 256 + threadIdx.x, w_off, w_def, wdef_ap, woff_ap);
}

// NCHW f32 -> NHWC f16 for all 4 batches, plus weight prep (merged launch).
__global__ void k_xprep(const float* __restrict__ x, f16* __restrict__ xt,
                        const float* __restrict__ w_off,
                        const float* __restrict__ w_def,
                        f16* __restrict__ wdef_ap,
                        f16* __restrict__ woff_ap) {
    int p = blockIdx.x * 256 + threadIdx.x;
    prep_elem(p, w_off, w_def, wdef_ap, woff_ap);
    int b = p >> 14, hw = p & 16383;
    const float* xb = x + (size_t)b * 64 * HWB + hw;
    f16x8 r[8];
    #pragma unroll
    for (int c = 0; c < 64; ++c) r[c >> 3][c & 7] = (f16)xb[(size_t)c * HWB];
    f16* ob = xt + (size_t)p * 64;
    #pragma unroll
    for (int q = 0; q < 8; ++q) *(f16x8*)(ob + q * 8) = r[q];
}

// NCHW f32 (slice) -> NHWC f16 (fallback path, per batch).
__global__ void k_xpose(const float* __restrict__ x, f16* __restrict__ xt) {
    int p = blockIdx.x * 256 + threadIdx.x;
    const float* xb = x + p;
    f16x8 r[8];
    #pragma unroll
    for (int c = 0; c < 64; ++c) r[c >> 3][c & 7] = (f16)xb[(size_t)c * HWB];
    f16* ob = xt + (size_t)p * 64;
    #pragma unroll
    for (int q = 0; q < 8; ++q) *(f16x8*)(ob + q * 8) = r[q];
}

// Block: 256 thr = 4 waves = 4 K-quarters (chq); 32 px per block.
// Round-13 structure + SHARED bilinear preloop: the 9*32 (kk,px) items are
// computed once per block (1 pass of 256 thr + 32-lane tail), stored with
// co=0 into a buffer aliasing dead red0; phase 1 reads wq (b64) + addrs
// (b128) and applies the per-lane ^co fix (base|bits4-6, co in bits 4-6).
__launch_bounds__(256, 4)
__global__ void k_fused(const f16* __restrict__ xt,      // NHWC f16 slice
                        const f16* __restrict__ woff_ap,
                        const float* __restrict__ b_off,
                        const f16* __restrict__ wdef_ap,
                        const float* __restrict__ b_def,
                        float* __restrict__ out, int bstart) {
    __shared__ __align__(16) char band[6 * 40 * 128];    // 30720 B
    __shared__ float offsm[18 * 33];                     // 2376 B
    __shared__ __align__(16) float red0[3 * 594];        // 7128 B (o<18)
    float* red1 = (float*)band;                          // [3][64][33] alias
    f16x4* wqbuf = (f16x4*)red0;                         // 9*32*8  = 2304 B alias
    u32x4* adbuf = (u32x4*)((char*)red0 + 2304);         // 9*32*16 = 4608 B alias

    int nwg = gridDim.x;
    int bid = blockIdx.x;
    int sb = (bid & 7) * (nwg >> 3) + (bid >> 3);        // bijective XCD swizzle
    int bl = sb >> 9, h = (sb >> 2) & 127, quarter = sb & 3;
    int b = bstart + bl;
    int s = quarter * 32;                                // block px start
    int tid = threadIdx.x;
    int lane = tid & 63, chq = tid >> 6;
    int px = lane & 31, half = lane >> 5;
    int pxb = s + px;

    const f16* xb = xt + (size_t)bl * HWB * 64;
    unsigned co = (unsigned)((chq * 2 + half) * 16);     // chunk byte off pre-XOR

    // ---------------- stage 6-row band via global_load_lds ----------------
    {
        int cell_lo = lane >> 3, cc = lane & 7;
        for (int gid = chq; gid < 30; gid += 4) {
            int r = gid / 5, seg = gid - (gid / 5) * 5;
            int cell0 = seg * 8;
            int cell = cell0 + cell_lo;
            int y = min(max(h - 2 + r, 0), 127);
            int xg = min(max(s - 2 + cell, 0), 127);
            int gg = cc ^ (cell & 7);
            const f16* gsrc = xb + (size_t)((y * 128 + xg) * 64 + gg * 8);
            char* ldst = band + (r * 40 + cell0) * 128;  // wave-uniform
            if (cell < 37)
                __builtin_amdgcn_global_load_lds(
                    (const __attribute__((address_space(1))) unsigned int*)gsrc,
                    (__attribute__((address_space(3))) unsigned int*)ldst,
                    16, 0, 0);
        }
    }
    __syncthreads();

    // -------- phase 0: offset conv, one 32-tile, K-quarter per wave -------
    f32x16 oacc = {};
    f16x8 zb = {};
    #pragma unroll
    for (int kk = 0; kk < 9; ++kk) {
        int ky = kk / 3 - 1, kx = kk - (kk / 3) * 3 - 1;
        int yy = h + ky, xx = pxb + kx;
        bool valid = ((unsigned)yy < 128u) && ((unsigned)xx < 128u);
        int ry = min(max(yy, 0), 127) - (h - 2);
        int cx = min(max(xx, 0), 127) - (s - 2);
        f16x8 B = *(const f16x8*)(band + (ry * 40 + cx) * 128 +
                                  (co ^ (((unsigned)cx & 7u) << 4)));
        B = valid ? B : zb;
        f16x8 A = *(const f16x8*)(woff_ap + ((size_t)(kk * 4 + chq) * 64 + lane) * 8);
        oacc = __builtin_amdgcn_mfma_f32_32x32x16_f16(A, B, oacc, 0, 0, 0);
    }
    if (chq != 0) {
        #pragma unroll
        for (int reg = 0; reg < 16; ++reg) {
            int row = (reg & 3) + 8 * (reg >> 2) + 4 * half;
            if (row < 18) red0[(chq - 1) * 594 + row * 33 + px] = oacc[reg];
        }
    }
    __syncthreads();
    if (chq == 0) {
        #pragma unroll
        for (int reg = 0; reg < 16; ++reg) {
            int row = (reg & 3) + 8 * (reg >> 2) + 4 * half;
            if (row < 18) {
                float v = oacc[reg] + red0[row * 33 + px] +
                          red0[594 + row * 33 + px] + red0[1188 + row * 33 + px] +
                          b_off[row];
                offsm[row * 33 + px] = fminf(fmaxf(v, -1.f), 1.f);
            }
        }
    }
    __syncthreads();   // offsm ready; red0 dead -> wqbuf/adbuf may be written

    // ------ shared preloop: 288 (kk,px) items, computed once per block ----
    {
        auto compute_bil = [&](int kk, int p) {
            float dy = offsm[(2 * kk) * 33 + p];
            float dx = offsm[(2 * kk + 1) * 33 + p];
            int ky = kk / 3 - 1, kx = kk - (kk / 3) * 3 - 1;
            float py = (float)(h + ky) + dy;
            float pxf = (float)(s + p + kx) + dx;
            float y0f = floorf(py), x0f = floorf(pxf);
            float ly = py - y0f, lx = pxf - x0f;
            int y0 = (int)y0f, x0 = (int)x0f;
            float vy0 = ((unsigned)y0 < 128u) ? 1.f : 0.f;
            float vy1 = ((unsigned)(y0 + 1) < 128u) ? 1.f : 0.f;
            float vx0 = ((unsigned)x0 < 128u) ? 1.f : 0.f;
            float vx1 = ((unsigned)(x0 + 1) < 128u) ? 1.f : 0.f;
            f16x4 wv;
            wv[0] = (f16)((1.f - ly) * (1.f - lx) * vy0 * vx0);
            wv[1] = (f16)((1.f - ly) * lx * vy0 * vx1);
            wv[2] = (f16)(ly * (1.f - lx) * vy1 * vx0);
            wv[3] = (f16)(ly * lx * vy1 * vx1);
            int yc0 = min(max(y0, 0), 127), yc1 = min(max(y0 + 1, 0), 127);
            int xc0 = min(max(x0, 0), 127), xc1 = min(max(x0 + 1, 0), 127);
            int ry0 = yc0 - (h - 2), ry1 = yc1 - (h - 2);
            int cx0 = xc0 - (s - 2), cx1 = xc1 - (s - 2);
            unsigned s0 = ((unsigned)cx0 & 7u) << 4;     // co=0 base
            unsigned s1 = ((unsigned)cx1 & 7u) << 4;
            u32x4 ad;
            ad[0] = (unsigned)((ry0 * 40 + cx0) * 128) + s0;
            ad[1] = (unsigned)((ry0 * 40 + cx1) * 128) + s1;
            ad[2] = (unsigned)((ry1 * 40 + cx0) * 128) + s0;
            ad[3] = (unsigned)((ry1 * 40 + cx1) * 128) + s1;
            wqbuf[kk * 32 + p] = wv;
            adbuf[kk * 32 + p] = ad;
        };
        compute_bil(tid >> 5, tid & 31);                 // kk 0..7
        if (tid < 32) compute_bil(8, tid);               // tail: kk 8 (wave 0)
    }
    __syncthreads();

    // ------ phase 1 main: shared addrs ^co -> gathers -> interp -> MFMA ---
    f32x16 acc0 = {}, acc1 = {};
    #pragma unroll
    for (int kk = 0; kk < 9; ++kk) {
        f16x4 wv = wqbuf[kk * 32 + px];
        u32x4 ad = adbuf[kk * 32 + px];
        f16x8 c00 = *(const f16x8*)(band + (ad[0] ^ co));
        f16x8 c01 = *(const f16x8*)(band + (ad[1] ^ co));
        f16x8 c10 = *(const f16x8*)(band + (ad[2] ^ co));
        f16x8 c11 = *(const f16x8*)(band + (ad[3] ^ co));
        f16x8 B = c00 * wv[0] + c01 * wv[1] + c10 * wv[2] + c11 * wv[3];
        size_t tb = (size_t)((kk * 4 + chq) * 2) * 64 * 8;
        f16x8 A0 = *(const f16x8*)(wdef_ap + tb + (size_t)lane * 8);
        f16x8 A1 = *(const f16x8*)(wdef_ap + tb + (size_t)(64 + lane) * 8);
        acc0 = __builtin_amdgcn_mfma_f32_32x32x16_f16(A0, B, acc0, 0, 0, 0);
        acc1 = __builtin_amdgcn_mfma_f32_32x32x16_f16(A1, B, acc1, 0, 0, 0);
    }

    __syncthreads();                  // band reads done -> red1 safe
    if (chq != 0) {
        #pragma unroll
        for (int m = 0; m < 2; ++m)
            #pragma unroll
            for (int reg = 0; reg < 16; ++reg) {
                int o = m * 32 + (reg & 3) + 8 * (reg >> 2) + 4 * half;
                float v = m ? acc1[reg] : acc0[reg];
                red1[(chq - 1) * 2112 + o * 33 + px] = v;
            }
    }
    __syncthreads();
    if (chq == 0) {
        #pragma unroll
        for (int m = 0; m < 2; ++m)
            #pragma unroll
            for (int reg = 0; reg < 16; ++reg) {
                int o = m * 32 + (reg & 3) + 8 * (reg >> 2) + 4 * half;
                float v = (m ? acc1[reg] : acc0[reg]) +
                          red1[o * 33 + px] + red1[2112 + o * 33 + px] +
                          red1[4224 + o * 33 + px] + b_def[o];
                out[(size_t)(b * 64 + o) * HWB + h * 128 + pxb] = v;
            }
    }
}

extern "C" void kernel_launch(void* const* d_in, const int* in_sizes, int n_in,
                              void* d_out, int out_size, void* d_ws, size_t ws_size,
                              hipStream_t stream) {
    const float* x     = (const float*)d_in[0];
    const float* w_off = (const float*)d_in[1];
    const float* b_off = (const float*)d_in[2];
    const float* w_def = (const float*)d_in[3];
    const float* b_def = (const float*)d_in[4];
    float* out = (float*)d_out;

    char* wsb = (char*)d_ws;
    f16* wdef_ap = (f16*)wsb;                    // 73728 B
    f16* woff_ap = (f16*)(wsb + 73728);          // 36864 B
    f16* xt      = (f16*)(wsb + 110592);         // NHWC f16

    if (ws_size >= (size_t)110592 + 8388608) {
        // single shot: prep + all-batch transpose merged, then fused kernel
        k_xprep<<<256, 256, 0, stream>>>(x, xt, w_off, w_def, wdef_ap, woff_ap);
        k_fused<<<2048, 256, 0, stream>>>(xt, woff_ap, b_off, wdef_ap, b_def, out, 0);
    } else {
        // batch-sliced fallback (2.1 MB slice, stream-ordered)
        k_prep<<<216, 256, 0, stream>>>(w_off, w_def, wdef_ap, woff_ap);
        for (int b = 0; b < 4; ++b) {
            k_xpose<<<64, 256, 0, stream>>>(x + (size_t)b * 64 * HWB, xt);
            k_fused<<<512, 256, 0, stream>>>(xt, woff_ap, b_off, wdef_ap, b_def, out, b);
        }
    }
}